// Round 6
// baseline (463.961 us; speedup 1.0000x reference)
//
#include <hip/hip_runtime.h>
#include <math.h>

#define NG   90
#define PD   96
#define STRD 100
#define ARR  (PD*STRD)     // 9600 floats per LDS slot
#define KK   10
#define NB   256
#define NTOT (NB*NG)       // 23040
#define EPG  8010
#define SM_FLOATS (4*ARR)  // 153,600 B dynamic LDS

__device__ __forceinline__ float agent_loadf(const float* p) {
    return __hip_atomic_load(p, __ATOMIC_RELAXED, __HIP_MEMORY_SCOPE_AGENT);
}

__global__ __launch_bounds__(1024, 4)
void mega_kernel(const float* __restrict__ x, const float* __restrict__ attr,
                 const float* __restrict__ W1m, const float* __restrict__ W1r, const float* __restrict__ b1,
                 const float* __restrict__ W2m, const float* __restrict__ W2r, const float* __restrict__ b2,
                 const float* __restrict__ poolp, const float* __restrict__ linW, const float* __restrict__ linb,
                 const float* __restrict__ clsW, const float* __restrict__ clsb,
                 float* __restrict__ gstats, float* __restrict__ vlin, float* __restrict__ scal,
                 unsigned int* __restrict__ bar, float* __restrict__ out)
{
    extern __shared__ float sm[];
    float* s0  = sm;              // X -> M^T -> X2 -> M2^T -> BN(h2)
    float* sA  = s0 + ARR;        // A[d][s], persistent across both layers
    float* sWm = sA + ARR;        // Wm^T[c][k]
    float* sWr = sWm + ARR;       // Wr^T[c][k]
    __shared__ float sSum[96], sSq[96];
    __shared__ float sScore[96], sP[96];
    __shared__ float sVal[KK];
    __shared__ int   sIdx[KK];
    __shared__ float sRed[16];

    const int g = blockIdx.x, tid = threadIdx.x;
    const int lane = tid & 63, wave = tid >> 6;
    const int lr = (lane >> 3) & 7, lc = lane & 7;
    const int r0 = ((wave >> 2) * 8 + lr) * 3;   // 0..93
    const int c0 = ((wave & 3) * 8 + lc) * 3;    // 0..93

    if (tid < 96) { sSum[tid] = 0.f; sSq[tid] = 0.f; }
    if (tid < NG) sP[tid] = poolp[tid];

    // ---- stage X (row-major, coalesced global + coalesced LDS) ----
    for (int idx = tid; idx < PD * PD; idx += 1024) {
        int r = idx / PD, k = idx - (idx / PD) * PD;
        s0[r * STRD + k] = (r < NG && k < NG) ? x[(size_t)(g * NG + r) * NG + k] : 0.f;
    }
    // ---- stage A[d][s]: iterate s-major so global attr reads are coalesced ----
    for (int idx = tid; idx < PD * PD; idx += 1024) {
        int s = idx / PD, d = idx - (idx / PD) * PD;
        float v = 0.f;
        if (s < NG && d < NG && d != s) v = attr[(size_t)g * EPG + s * 89 + (d > s ? d - 1 : d)];
        sA[d * STRD + s] = v;
    }
    // ---- stage W1^T: iterate k-major so global W reads are coalesced ----
    for (int idx = tid; idx < PD * PD; idx += 1024) {
        int k = idx / PD, c = idx - (idx / PD) * PD;
        bool ok = (k < NG && c < NG);
        sWm[c * STRD + k] = ok ? W1m[k * NG + c] : 0.f;
        sWr[c * STRD + k] = ok ? W1r[k * NG + c] : 0.f;
    }
    __syncthreads();

    float h[3][3];

    for (int layer = 0; layer < 2; ++layer) {
        // ---- fused GEMM1: accM = X@Wm, accR = X@Wr (X read once) ----
        float accM[3][3] = {{0.f,0.f,0.f},{0.f,0.f,0.f},{0.f,0.f,0.f}};
        float accR[3][3] = {{0.f,0.f,0.f},{0.f,0.f,0.f},{0.f,0.f,0.f}};
        {
            const float* pX = s0  + r0 * STRD;
            const float* pm = sWm + c0 * STRD;
            const float* pr = sWr + c0 * STRD;
#pragma unroll 2
            for (int k = 0; k < PD; k += 4) {
                float4 xv[3], wm[3], wr[3];
#pragma unroll
                for (int i = 0; i < 3; i++) xv[i] = *(const float4*)(pX + i * STRD + k);
#pragma unroll
                for (int j = 0; j < 3; j++) {
                    wm[j] = *(const float4*)(pm + j * STRD + k);
                    wr[j] = *(const float4*)(pr + j * STRD + k);
                }
#pragma unroll
                for (int i = 0; i < 3; i++)
#pragma unroll
                    for (int j = 0; j < 3; j++) {
                        accM[i][j] = fmaf(xv[i].x, wm[j].x, accM[i][j]);
                        accM[i][j] = fmaf(xv[i].y, wm[j].y, accM[i][j]);
                        accM[i][j] = fmaf(xv[i].z, wm[j].z, accM[i][j]);
                        accM[i][j] = fmaf(xv[i].w, wm[j].w, accM[i][j]);
                        accR[i][j] = fmaf(xv[i].x, wr[j].x, accR[i][j]);
                        accR[i][j] = fmaf(xv[i].y, wr[j].y, accR[i][j]);
                        accR[i][j] = fmaf(xv[i].z, wr[j].z, accR[i][j]);
                        accR[i][j] = fmaf(xv[i].w, wr[j].w, accR[i][j]);
                    }
            }
        }
        __syncthreads();   // GEMM1 reads of s0 done
        // M^T into s0
#pragma unroll
        for (int j = 0; j < 3; j++)
#pragma unroll
            for (int i = 0; i < 3; i++)
                s0[(c0 + j) * STRD + (r0 + i)] = accM[i][j];
        __syncthreads();   // M visible

        // ---- GEMM2: h = bias + R + A@M ----
        const float* bias = layer ? b2 : b1;
#pragma unroll
        for (int j = 0; j < 3; j++) {
            float bj = (c0 + j < NG) ? bias[c0 + j] : 0.f;
#pragma unroll
            for (int i = 0; i < 3; i++) h[i][j] = accR[i][j] + bj;
        }
        {
            const float* pA = sA + r0 * STRD;
            const float* pM = s0 + c0 * STRD;
#pragma unroll 2
            for (int k = 0; k < PD; k += 4) {
                float4 av[3], mv[3];
#pragma unroll
                for (int i = 0; i < 3; i++) av[i] = *(const float4*)(pA + i * STRD + k);
#pragma unroll
                for (int j = 0; j < 3; j++) mv[j] = *(const float4*)(pM + j * STRD + k);
#pragma unroll
                for (int i = 0; i < 3; i++)
#pragma unroll
                    for (int j = 0; j < 3; j++) {
                        h[i][j] = fmaf(av[i].x, mv[j].x, h[i][j]);
                        h[i][j] = fmaf(av[i].y, mv[j].y, h[i][j]);
                        h[i][j] = fmaf(av[i].z, mv[j].z, h[i][j]);
                        h[i][j] = fmaf(av[i].w, mv[j].w, h[i][j]);
                    }
            }
        }

        // ---- relu + BN partial stats ----
        float cs[3] = {0.f,0.f,0.f}, cq[3] = {0.f,0.f,0.f};
#pragma unroll
        for (int i = 0; i < 3; i++) {
            int r = r0 + i;
#pragma unroll
            for (int j = 0; j < 3; j++) {
                float v = fmaxf(h[i][j], 0.f);
                h[i][j] = v;
                if (r < NG && c0 + j < NG) { cs[j] += v; cq[j] += v * v; }
            }
        }
#pragma unroll
        for (int m = 8; m < 64; m <<= 1) {
#pragma unroll
            for (int j = 0; j < 3; j++) {
                cs[j] += __shfl_xor(cs[j], m);
                cq[j] += __shfl_xor(cq[j], m);
            }
        }
        if (lr == 0) {
#pragma unroll
            for (int j = 0; j < 3; j++) {
                int c = c0 + j;
                if (c < NG) { atomicAdd(&sSum[c], cs[j]); atomicAdd(&sSq[c], cq[j]); }
            }
        }
        __syncthreads();
        float* gs = gstats + layer * 192;
        if (tid < NG) { atomicAdd(&gs[tid], sSum[tid]); atomicAdd(&gs[96 + tid], sSq[tid]); }
        __syncthreads();

        // ---- device-wide barrier (release/acquire), work hidden in wait ----
        if (tid == 0)
            __hip_atomic_fetch_add(&bar[layer], 1u, __ATOMIC_RELEASE, __HIP_MEMORY_SCOPE_AGENT);
        if (layer == 0) {
            // vlin prep during barrier wait: 900 rows over blocks 0..224 (4 waves each)
            if (g < 225) {
                if (wave < 4) {
                    int row = g * 4 + wave;
                    const float* rw = linW + (size_t)row * 1801;
                    float acc = 0.f;
                    for (int c2 = lane; c2 < 1801; c2 += 64) acc += rw[c2] * clsW[c2];
                    for (int off = 32; off; off >>= 1) acc += __shfl_down(acc, off);
                    if (lane == 0) vlin[row] = acc;
                }
            } else if (g == 255) {
                if (wave == 0) {
                    float acc = 0.f;
                    for (int c2 = lane; c2 < 1801; c2 += 64) acc += linb[c2] * clsW[c2];
                    for (int off = 32; off; off >>= 1) acc += __shfl_down(acc, off);
                    if (lane == 0) scal[0] = acc + clsb[0];
                } else if (wave == 1) {
                    float acc = 0.f;
                    for (int c2 = lane; c2 < NG; c2 += 64) acc += poolp[c2] * poolp[c2];
                    for (int off = 32; off; off >>= 1) acc += __shfl_down(acc, off);
                    if (lane == 0) scal[1] = rsqrtf(acc);
                }
            }
        }
        if (tid == 0) {
            int it = 0;
            while (__hip_atomic_load(&bar[layer], __ATOMIC_ACQUIRE, __HIP_MEMORY_SCOPE_AGENT) < (unsigned)NB) {
                __builtin_amdgcn_s_sleep(4);
                if (++it > 300000) break;   // safety valve: wrong answer beats a hung container
            }
        }
        __syncthreads();

        // ---- apply global BN to register h, write as next layer's X (pad=0) ----
        float mu[3], rs[3];
#pragma unroll
        for (int j = 0; j < 3; j++) {
            int c = c0 + j;
            float s1 = agent_loadf(gs + c), s2 = agent_loadf(gs + 96 + c);
            float m = s1 * (1.f / NTOT);
            float v = s2 * (1.f / NTOT) - m * m;
            mu[j] = m; rs[j] = rsqrtf(v + 1e-5f);
        }
#pragma unroll
        for (int i = 0; i < 3; i++)
#pragma unroll
            for (int j = 0; j < 3; j++) {
                float v = (h[i][j] - mu[j]) * rs[j];
                s0[(r0 + i) * STRD + (c0 + j)] = (r0 + i < NG && c0 + j < NG) ? v : 0.f;
            }
        if (layer == 0) {
            if (tid < 96) { sSum[tid] = 0.f; sSq[tid] = 0.f; }
            for (int idx = tid; idx < PD * PD; idx += 1024) {
                int k = idx / PD, c = idx - (idx / PD) * PD;
                bool ok = (k < NG && c < NG);
                sWm[c * STRD + k] = ok ? W2m[k * NG + c] : 0.f;
                sWr[c * STRD + k] = ok ? W2r[k * NG + c] : 0.f;
            }
        }
        __syncthreads();
    }

    // ---------- phase C: s0 holds BN(h2); score, top-k, classifier ----------
    float sc1 = agent_loadf(scal + 1);
    if (tid < NG) {
        float s = 0.f;
        for (int f = 0; f < NG; f++) s += s0[tid * STRD + f] * sP[f];
        sScore[tid] = 0.7f * tanhf(s * sc1);
    }
    __syncthreads();

    if (tid < 64) {   // wave-parallel top-10, ties -> lower index (lax.top_k)
        float va = sScore[tid];
        float vb = (tid + 64 < NG) ? sScore[tid + 64] : -1e30f;
        int ia = tid, ib = tid + 64;
        for (int k = 0; k < KK; k++) {
            float v; int i;
            if (va >= vb) { v = va; i = ia; } else { v = vb; i = ib; }
            for (int off = 1; off < 64; off <<= 1) {
                float v2 = __shfl_xor(v, off);
                int   i2 = __shfl_xor(i, off);
                if (v2 > v || (v2 == v && i2 < i)) { v = v2; i = i2; }
            }
            if (tid == 0) { sIdx[k] = i; sVal[k] = v; }
            if (i == ia) va = -1e30f;
            if (i == ib) vb = -1e30f;
        }
    }
    __syncthreads();

    if (tid < KK) out[NB + g * KK + tid] = (float)(g * NG + sIdx[tid]);

    float acc = 0.f;
    if (tid < KK * NG) {
        int k = tid / NG, f = tid - (tid / NG) * NG;
        acc = s0[sIdx[k] * STRD + f] * sVal[k] * agent_loadf(vlin + tid);
    }
    for (int off = 32; off; off >>= 1) acc += __shfl_down(acc, off);
    if (lane == 0) sRed[wave] = acc;
    __syncthreads();
    if (tid == 0) {
        float tot = agent_loadf(scal);
#pragma unroll
        for (int w = 0; w < 16; w++) tot += sRed[w];
        out[g] = 1.f / (1.f + expf(-tot));
    }
}

// ---------------- host launch ----------------
extern "C" void kernel_launch(void* const* d_in, const int* in_sizes, int n_in,
                              void* d_out, int out_size, void* d_ws, size_t ws_size,
                              hipStream_t stream) {
    const float* x    = (const float*)d_in[0];
    const float* attr = (const float*)d_in[2];
    const float* W1r  = (const float*)d_in[4];
    const float* W1m  = (const float*)d_in[5];
    const float* b1   = (const float*)d_in[6];
    const float* W2r  = (const float*)d_in[7];
    const float* W2m  = (const float*)d_in[8];
    const float* b2   = (const float*)d_in[9];
    const float* poolp= (const float*)d_in[10];
    const float* linW = (const float*)d_in[11];
    const float* linb = (const float*)d_in[12];
    const float* clsW = (const float*)d_in[13];
    const float* clsb = (const float*)d_in[14];

    float* ws       = (float*)d_ws;
    float* gstats   = ws;                      // 384 (sum1,sq1 | sum2,sq2)
    unsigned int* bar = (unsigned int*)(ws + 384);  // 8
    float* vlin     = ws + 392;                // 900
    float* scal     = ws + 1292;               // 2
    float* out      = (float*)d_out;

    hipMemsetAsync(ws, 0, 392 * sizeof(float), stream);   // gstats + barrier counters

    const size_t smem = SM_FLOATS * sizeof(float);        // 153,600 B
    hipFuncSetAttribute((const void*)mega_kernel, hipFuncAttributeMaxDynamicSharedMemorySize, (int)smem);

    mega_kernel<<<NB, 1024, smem, stream>>>(x, attr, W1m, W1r, b1, W2m, W2r, b2,
                                            poolp, linW, linb, clsW, clsb,
                                            gstats, vlin, scal, bar, out);
}

// Round 8
// 234.351 us; speedup vs baseline: 1.9798x; 1.9798x over previous
//
#include <hip/hip_runtime.h>
#include <math.h>

#define NG   90
#define PD   96
#define STRD 100
#define KK   10
#define NB   256
#define NTOT (NB*NG)   // 23040
#define EPG  8010
#define ARR  (PD*STRD)
#define SM_FLOATS (4*ARR)   // 153,600 B dynamic LDS

// ---------------- conv+BN-stats layer: one graph per block ----------------
// 512 threads = 8 waves (2/SIMD via __launch_bounds__ min-waves hint).
// Thread tile: 3 rows x 6 cols, cols interleaved stride 16 (c_j = cg + 16*j).
__global__ __launch_bounds__(512, 2)
void layer_kernel(const float* __restrict__ xin,
                  const float* __restrict__ psIn, int apply_bn,
                  const float* __restrict__ attr,
                  const float* __restrict__ Wm, const float* __restrict__ Wr,
                  const float* __restrict__ bias,
                  float* __restrict__ hout, float* __restrict__ psOut,
                  int do_prep,
                  const float* __restrict__ linW, const float* __restrict__ linb,
                  const float* __restrict__ clsW, const float* __restrict__ clsb,
                  const float* __restrict__ poolp,
                  float* __restrict__ vlin, float* __restrict__ scal)
{
    extern __shared__ float sm[];
    float* s0  = sm;            // X (BN applied), then M^T[c][r]
    float* sA  = s0 + ARR;      // A[d][s]
    float* sWm = sA + ARR;      // Wm^T[c][k]
    float* sWr = sWm + ARR;     // Wr^T[c][k]
    __shared__ float sSum[96], sSq[96], sMu[96], sRs[96], sStat[192];

    const int g = blockIdx.x, tid = threadIdx.x;
    const int lane = tid & 63, wave = tid >> 6;
    const int cg = tid & 15;          // col group: cols cg+16j
    const int rg = tid >> 4;          // row group 0..31
    const int r0 = rg * 3;

    // ---- BN stats of input: reduce previous layer's per-block partials ----
    if (apply_bn) {
        if (tid < 192) {
            float s = 0.f;
            const float* p = psIn + tid;
#pragma unroll 8
            for (int b = 0; b < NB; b++) s += p[b * 192];
            sStat[tid] = s;
        }
        __syncthreads();
        if (tid < 96) {
            float m = sStat[tid] * (1.f / NTOT);
            float v = sStat[96 + tid] * (1.f / NTOT) - m * m;
            sMu[tid] = m; sRs[tid] = rsqrtf(v + 1e-5f);
        }
    } else if (tid < 96) { sMu[tid] = 0.f; sRs[tid] = 1.f; }
    if (tid < 96) { sSum[tid] = 0.f; sSq[tid] = 0.f; }
    __syncthreads();

    // ---- stage X (BN applied, zero-padded to 96x96) ----
    for (int idx = tid; idx < PD * PD; idx += 512) {
        int r = idx / PD, k = idx - (idx / PD) * PD;
        float v = 0.f;
        if (r < NG && k < NG) v = (xin[(size_t)(g * NG + r) * NG + k] - sMu[k]) * sRs[k];
        s0[r * STRD + k] = v;
    }
    // ---- stage A[d][s] (closed-form from dense edge list; coalesced attr) ----
    for (int idx = tid; idx < PD * PD; idx += 512) {
        int s = idx / PD, d = idx - (idx / PD) * PD;
        float v = 0.f;
        if (s < NG && d < NG && d != s) v = attr[(size_t)g * EPG + s * 89 + (d > s ? d - 1 : d)];
        sA[d * STRD + s] = v;
    }
    // ---- stage Wm^T, Wr^T [c][k] (coalesced global reads) ----
    for (int idx = tid; idx < PD * PD; idx += 512) {
        int k = idx / PD, c = idx - (idx / PD) * PD;
        bool ok = (k < NG && c < NG);
        sWm[c * STRD + k] = ok ? Wm[k * NG + c] : 0.f;
        sWr[c * STRD + k] = ok ? Wr[k * NG + c] : 0.f;
    }
    __syncthreads();   // B1

    // ---- fused GEMM1: accM = X@Wm, accR = X@Wr ----
    float accM[3][6], accR[3][6];
#pragma unroll
    for (int i = 0; i < 3; i++)
#pragma unroll
        for (int j = 0; j < 6; j++) { accM[i][j] = 0.f; accR[i][j] = 0.f; }
    {
        const float* pX = s0 + r0 * STRD;
#pragma unroll 2
        for (int k = 0; k < PD; k += 4) {
            float4 xv[3], wm[6], wr[6];
#pragma unroll
            for (int i = 0; i < 3; i++) xv[i] = *(const float4*)(pX + i * STRD + k);
#pragma unroll
            for (int j = 0; j < 6; j++) {
                const int c = cg + 16 * j;
                wm[j] = *(const float4*)(sWm + c * STRD + k);
                wr[j] = *(const float4*)(sWr + c * STRD + k);
            }
#pragma unroll
            for (int i = 0; i < 3; i++)
#pragma unroll
                for (int j = 0; j < 6; j++) {
                    accM[i][j] = fmaf(xv[i].x, wm[j].x, accM[i][j]);
                    accM[i][j] = fmaf(xv[i].y, wm[j].y, accM[i][j]);
                    accM[i][j] = fmaf(xv[i].z, wm[j].z, accM[i][j]);
                    accM[i][j] = fmaf(xv[i].w, wm[j].w, accM[i][j]);
                    accR[i][j] = fmaf(xv[i].x, wr[j].x, accR[i][j]);
                    accR[i][j] = fmaf(xv[i].y, wr[j].y, accR[i][j]);
                    accR[i][j] = fmaf(xv[i].z, wr[j].z, accR[i][j]);
                    accR[i][j] = fmaf(xv[i].w, wr[j].w, accR[i][j]);
                }
        }
    }
    __syncthreads();   // B2: GEMM1 reads of s0 done

    // write M^T[c][r] into s0
#pragma unroll
    for (int j = 0; j < 6; j++)
#pragma unroll
        for (int i = 0; i < 3; i++)
            s0[(cg + 16 * j) * STRD + (r0 + i)] = accM[i][j];
    __syncthreads();   // B3: M visible

    // ---- GEMM2: h = bias + R + A@M ----
    float h[3][6];
#pragma unroll
    for (int j = 0; j < 6; j++) {
        const int c = cg + 16 * j;
        float bj = (c < NG) ? bias[c] : 0.f;
#pragma unroll
        for (int i = 0; i < 3; i++) h[i][j] = accR[i][j] + bj;
    }
    {
        const float* pA = sA + r0 * STRD;
#pragma unroll 2
        for (int k = 0; k < PD; k += 4) {
            float4 av[3], mv[6];
#pragma unroll
            for (int i = 0; i < 3; i++) av[i] = *(const float4*)(pA + i * STRD + k);
#pragma unroll
            for (int j = 0; j < 6; j++) mv[j] = *(const float4*)(s0 + (cg + 16 * j) * STRD + k);
#pragma unroll
            for (int i = 0; i < 3; i++)
#pragma unroll
                for (int j = 0; j < 6; j++) {
                    h[i][j] = fmaf(av[i].x, mv[j].x, h[i][j]);
                    h[i][j] = fmaf(av[i].y, mv[j].y, h[i][j]);
                    h[i][j] = fmaf(av[i].z, mv[j].z, h[i][j]);
                    h[i][j] = fmaf(av[i].w, mv[j].w, h[i][j]);
                }
        }
    }

    // ---- relu + global store + BN partial stats ----
    float cs[6], cq[6];
#pragma unroll
    for (int j = 0; j < 6; j++) { cs[j] = 0.f; cq[j] = 0.f; }
#pragma unroll
    for (int i = 0; i < 3; i++) {
        int r = r0 + i;
        if (r < NG) {
#pragma unroll
            for (int j = 0; j < 6; j++) {
                int c = cg + 16 * j;
                if (c < NG) {
                    float v = fmaxf(h[i][j], 0.f);
                    hout[(size_t)(g * NG + r) * NG + c] = v;
                    cs[j] += v; cq[j] += v * v;
                }
            }
        }
    }
#pragma unroll
    for (int m = 16; m < 64; m <<= 1) {
#pragma unroll
        for (int j = 0; j < 6; j++) {
            cs[j] += __shfl_xor(cs[j], m);
            cq[j] += __shfl_xor(cq[j], m);
        }
    }
    if ((lane >> 4) == 0) {
#pragma unroll
        for (int j = 0; j < 6; j++) {
            int c = cg + 16 * j;
            if (c < NG) { atomicAdd(&sSum[c], cs[j]); atomicAdd(&sSq[c], cq[j]); }
        }
    }
    __syncthreads();
    // per-block partials (plain stores -> no global zero-init needed)
    if (tid < 96) psOut[g * 192 + tid] = sSum[tid];
    else if (tid < 192) psOut[g * 192 + tid] = sSq[tid - 96];

    // ---- folded classifier prep (layer 1 only), balanced across blocks ----
    if (do_prep) {
        if (wave < 4) {
            int row = g + 256 * wave;
            if (row < 900) {
                const float* rw = linW + (size_t)row * 1801;
                float acc = 0.f;
                for (int c2 = lane; c2 < 1801; c2 += 64) acc += rw[c2] * clsW[c2];
                for (int off = 32; off; off >>= 1) acc += __shfl_down(acc, off);
                if (lane == 0) vlin[row] = acc;
            }
        } else if (g == 0 && wave == 4) {
            float acc = 0.f;
            for (int c2 = lane; c2 < 1801; c2 += 64) acc += linb[c2] * clsW[c2];
            for (int off = 32; off; off >>= 1) acc += __shfl_down(acc, off);
            if (lane == 0) scal[0] = acc + clsb[0];
        } else if (g == 0 && wave == 5) {
            float acc = 0.f;
            for (int c2 = lane; c2 < NG; c2 += 64) acc += poolp[c2] * poolp[c2];
            for (int off = 32; off; off >>= 1) acc += __shfl_down(acc, off);
            if (lane == 0) scal[1] = rsqrtf(acc);
        }
    }
}

// ---------------- pooling + classifier ----------------
__global__ __launch_bounds__(256)
void final_kernel(const float* __restrict__ h2, const float* __restrict__ psIn,
                  const float* __restrict__ poolp,
                  const float* __restrict__ vlin, const float* __restrict__ scal,
                  float* __restrict__ out)
{
    __shared__ float sXN[NG * 91];
    __shared__ float sMu[96], sRs[96], sP[96], sStat[192];
    __shared__ float sScore[NG];
    __shared__ int   sIdx[KK];
    __shared__ float sVal[KK];
    __shared__ float sRed[4];
    const int g = blockIdx.x, tid = threadIdx.x;

    if (tid < 192) {
        float s = 0.f;
        const float* p = psIn + tid;
#pragma unroll 8
        for (int b = 0; b < NB; b++) s += p[b * 192];
        sStat[tid] = s;
    }
    __syncthreads();
    if (tid < NG) {
        float m = sStat[tid] * (1.f / NTOT);
        float v = sStat[96 + tid] * (1.f / NTOT) - m * m;
        sMu[tid] = m; sRs[tid] = rsqrtf(v + 1e-5f);
        sP[tid] = poolp[tid];
    }
    __syncthreads();

    const float* hg = h2 + (size_t)g * (NG * NG);
    for (int idx = tid; idx < NG * NG; idx += 256) {
        int d = idx / NG, f = idx - (idx / NG) * NG;
        sXN[d * 91 + f] = (hg[idx] - sMu[f]) * sRs[f];
    }
    __syncthreads();

    if (tid < NG) {
        float s = 0.f;
        for (int f = 0; f < NG; f++) s += sXN[tid * 91 + f] * sP[f];
        sScore[tid] = 0.7f * tanhf(s * scal[1]);
    }
    __syncthreads();

    // wave-parallel top-10 (ties -> lower index, matching lax.top_k)
    if (tid < 64) {
        float va = sScore[tid];
        float vb = (tid + 64 < NG) ? sScore[tid + 64] : -1e30f;
        int ia = tid, ib = tid + 64;
        for (int k = 0; k < KK; k++) {
            float v; int i;
            if (va >= vb) { v = va; i = ia; } else { v = vb; i = ib; }
            for (int off = 1; off < 64; off <<= 1) {
                float v2 = __shfl_xor(v, off);
                int   i2 = __shfl_xor(i, off);
                if (v2 > v || (v2 == v && i2 < i)) { v = v2; i = i2; }
            }
            if (tid == 0) { sIdx[k] = i; sVal[k] = v; }
            if (i == ia) va = -1e30f;
            if (i == ib) vb = -1e30f;
        }
    }
    __syncthreads();

    if (tid < KK) out[NB + g * KK + tid] = (float)(g * NG + sIdx[tid]);

    float acc = 0.f;
    for (int j = tid; j < KK * NG; j += 256) {
        int k = j / NG, f = j - (j / NG) * NG;
        acc += sXN[sIdx[k] * 91 + f] * sVal[k] * vlin[j];
    }
    for (int off = 32; off; off >>= 1) acc += __shfl_down(acc, off);
    if ((tid & 63) == 0) sRed[tid >> 6] = acc;
    __syncthreads();
    if (tid == 0) {
        float tot = sRed[0] + sRed[1] + sRed[2] + sRed[3] + scal[0];
        out[g] = 1.f / (1.f + expf(-tot));
    }
}

// ---------------- host launch ----------------
extern "C" void kernel_launch(void* const* d_in, const int* in_sizes, int n_in,
                              void* d_out, int out_size, void* d_ws, size_t ws_size,
                              hipStream_t stream) {
    const float* x    = (const float*)d_in[0];
    const float* attr = (const float*)d_in[2];
    const float* W1r  = (const float*)d_in[4];
    const float* W1m  = (const float*)d_in[5];
    const float* b1   = (const float*)d_in[6];
    const float* W2r  = (const float*)d_in[7];
    const float* W2m  = (const float*)d_in[8];
    const float* b2   = (const float*)d_in[9];
    const float* poolp= (const float*)d_in[10];
    const float* linW = (const float*)d_in[11];
    const float* linb = (const float*)d_in[12];
    const float* clsW = (const float*)d_in[13];
    const float* clsb = (const float*)d_in[14];

    float* ws   = (float*)d_ws;
    float* ps1  = ws;                         // 256*192 per-block stats, layer1
    float* ps2  = ps1 + NB * 192;             // 256*192, layer2
    float* vlin = ps2 + NB * 192;             // 900
    float* scal = vlin + 900;                 // 2
    float* h1   = scal + 62;                  // align; 23040*90
    float* h2   = h1 + (size_t)NTOT * NG;

    const size_t smem = SM_FLOATS * sizeof(float);   // 153,600 B
    hipFuncSetAttribute((const void*)layer_kernel, hipFuncAttributeMaxDynamicSharedMemorySize, (int)smem);

    layer_kernel<<<NB, 512, smem, stream>>>(x,  nullptr, 0, attr, W1m, W1r, b1, h1, ps1,
                                            1, linW, linb, clsW, clsb, poolp, vlin, scal);
    layer_kernel<<<NB, 512, smem, stream>>>(h1, ps1, 1, attr, W2m, W2r, b2, h2, ps2,
                                            0, linW, linb, clsW, clsb, poolp, vlin, scal);
    final_kernel<<<NB, 256, 0, stream>>>(h2, ps2, poolp, vlin, scal, (float*)d_out);
}

// Round 9
// 212.417 us; speedup vs baseline: 2.1842x; 1.1033x over previous
//
#include <hip/hip_runtime.h>
#include <math.h>

#define NG   90
#define PD   96
#define STRD 100
#define KK   10
#define NB   256
#define NTOT (NB*NG)   // 23040
#define EPG  8010
#define ARR  (PD*STRD)
#define SM_FLOATS (4*ARR)   // 153,600 B dynamic LDS

// ---------------- conv+BN-stats layer: one graph per block ----------------
// 1024 threads = 16 waves (4/SIMD). 8x8 lane grid per wave, 3x3 tile/thread.
// Fused GEMM1: accM=X@Wm, accR=X@Wr in one X pass; both GEMMs 2-stage
// software-pipelined (double-buffered ds_reads).
__global__ __launch_bounds__(1024, 4)
void layer_kernel(const float* __restrict__ xin,
                  const float* __restrict__ psIn, int apply_bn,
                  const float* __restrict__ attr,
                  const float* __restrict__ Wm, const float* __restrict__ Wr,
                  const float* __restrict__ bias,
                  float* __restrict__ hout, float* __restrict__ psOut,
                  int do_prep,
                  const float* __restrict__ linW, const float* __restrict__ linb,
                  const float* __restrict__ clsW, const float* __restrict__ clsb,
                  const float* __restrict__ poolp,
                  float* __restrict__ vlin, float* __restrict__ scal)
{
    extern __shared__ float sm[];
    float* s0  = sm;            // X (BN applied), then M^T[c][r]
    float* sA  = s0 + ARR;      // A[d][s]
    float* sWm = sA + ARR;      // Wm^T[c][k]
    float* sWr = sWm + ARR;     // Wr^T[c][k]
    __shared__ float sSum[96], sSq[96], sMu[96], sRs[96], sStat[192];

    const int g = blockIdx.x, tid = threadIdx.x;
    const int lane = tid & 63, wave = tid >> 6;
    const int lr = lane >> 3, lc = lane & 7;
    const int r0 = (wave >> 2) * 24 + lr * 3;   // 8 row-groups/wave -> banks 0,12,24,4,16,28,8,20 (conflict-free)
    const int c0 = (wave & 3) * 24 + lc * 3;    // same on the column side

    // ---- BN stats of input: reduce previous layer's per-block partials ----
    if (apply_bn) {
        if (tid < 192) {
            float s = 0.f;
            const float* p = psIn + tid;
#pragma unroll 8
            for (int b = 0; b < NB; b++) s += p[b * 192];
            sStat[tid] = s;
        }
        __syncthreads();
        if (tid < 96) {
            float m = sStat[tid] * (1.f / NTOT);
            float v = sStat[96 + tid] * (1.f / NTOT) - m * m;
            sMu[tid] = m; sRs[tid] = rsqrtf(v + 1e-5f);
        }
    } else if (tid < 96) { sMu[tid] = 0.f; sRs[tid] = 1.f; }
    if (tid < 96) { sSum[tid] = 0.f; sSq[tid] = 0.f; }
    __syncthreads();

    // ---- stage X (BN applied, zero-padded) ----
    for (int idx = tid; idx < PD * PD; idx += 1024) {
        int r = idx / PD, k = idx - (idx / PD) * PD;
        float v = 0.f;
        if (r < NG && k < NG) v = (xin[(size_t)(g * NG + r) * NG + k] - sMu[k]) * sRs[k];
        s0[r * STRD + k] = v;
    }
    // ---- stage A[d][s] (closed-form from dense edge list; coalesced attr) ----
    for (int idx = tid; idx < PD * PD; idx += 1024) {
        int s = idx / PD, d = idx - (idx / PD) * PD;
        float v = 0.f;
        if (s < NG && d < NG && d != s) v = attr[(size_t)g * EPG + s * 89 + (d > s ? d - 1 : d)];
        sA[d * STRD + s] = v;
    }
    // ---- stage Wm^T, Wr^T [c][k] (coalesced global reads) ----
    for (int idx = tid; idx < PD * PD; idx += 1024) {
        int k = idx / PD, c = idx - (idx / PD) * PD;
        bool ok = (k < NG && c < NG);
        sWm[c * STRD + k] = ok ? Wm[k * NG + c] : 0.f;
        sWr[c * STRD + k] = ok ? Wr[k * NG + c] : 0.f;
    }
    __syncthreads();   // B1

    // ---- fused GEMM1 (pipelined): accM = X@Wm, accR = X@Wr ----
    float accM[3][3] = {{0.f,0.f,0.f},{0.f,0.f,0.f},{0.f,0.f,0.f}};
    float accR[3][3] = {{0.f,0.f,0.f},{0.f,0.f,0.f},{0.f,0.f,0.f}};
    {
        const float* pX = s0  + r0 * STRD;
        const float* pm = sWm + c0 * STRD;
        const float* pr = sWr + c0 * STRD;
        float4 xa[3], ma[3], ra[3], xb[3], mb[3], rb[3];
#pragma unroll
        for (int i = 0; i < 3; i++) {
            xa[i] = *(const float4*)(pX + i * STRD);
            ma[i] = *(const float4*)(pm + i * STRD);
            ra[i] = *(const float4*)(pr + i * STRD);
        }
#pragma unroll 2
        for (int k = 0; k < 88; k += 8) {
#pragma unroll
            for (int i = 0; i < 3; i++) {
                xb[i] = *(const float4*)(pX + i * STRD + k + 4);
                mb[i] = *(const float4*)(pm + i * STRD + k + 4);
                rb[i] = *(const float4*)(pr + i * STRD + k + 4);
            }
#pragma unroll
            for (int i = 0; i < 3; i++)
#pragma unroll
                for (int j = 0; j < 3; j++) {
                    accM[i][j] = fmaf(xa[i].x, ma[j].x, accM[i][j]);
                    accM[i][j] = fmaf(xa[i].y, ma[j].y, accM[i][j]);
                    accM[i][j] = fmaf(xa[i].z, ma[j].z, accM[i][j]);
                    accM[i][j] = fmaf(xa[i].w, ma[j].w, accM[i][j]);
                    accR[i][j] = fmaf(xa[i].x, ra[j].x, accR[i][j]);
                    accR[i][j] = fmaf(xa[i].y, ra[j].y, accR[i][j]);
                    accR[i][j] = fmaf(xa[i].z, ra[j].z, accR[i][j]);
                    accR[i][j] = fmaf(xa[i].w, ra[j].w, accR[i][j]);
                }
#pragma unroll
            for (int i = 0; i < 3; i++) {
                xa[i] = *(const float4*)(pX + i * STRD + k + 8);
                ma[i] = *(const float4*)(pm + i * STRD + k + 8);
                ra[i] = *(const float4*)(pr + i * STRD + k + 8);
            }
#pragma unroll
            for (int i = 0; i < 3; i++)
#pragma unroll
                for (int j = 0; j < 3; j++) {
                    accM[i][j] = fmaf(xb[i].x, mb[j].x, accM[i][j]);
                    accM[i][j] = fmaf(xb[i].y, mb[j].y, accM[i][j]);
                    accM[i][j] = fmaf(xb[i].z, mb[j].z, accM[i][j]);
                    accM[i][j] = fmaf(xb[i].w, mb[j].w, accM[i][j]);
                    accR[i][j] = fmaf(xb[i].x, rb[j].x, accR[i][j]);
                    accR[i][j] = fmaf(xb[i].y, rb[j].y, accR[i][j]);
                    accR[i][j] = fmaf(xb[i].z, rb[j].z, accR[i][j]);
                    accR[i][j] = fmaf(xb[i].w, rb[j].w, accR[i][j]);
                }
        }
        // epilogue: quads 88 and 92
#pragma unroll
        for (int i = 0; i < 3; i++) {
            xb[i] = *(const float4*)(pX + i * STRD + 92);
            mb[i] = *(const float4*)(pm + i * STRD + 92);
            rb[i] = *(const float4*)(pr + i * STRD + 92);
        }
#pragma unroll
        for (int i = 0; i < 3; i++)
#pragma unroll
            for (int j = 0; j < 3; j++) {
                accM[i][j] = fmaf(xa[i].x, ma[j].x, accM[i][j]);
                accM[i][j] = fmaf(xa[i].y, ma[j].y, accM[i][j]);
                accM[i][j] = fmaf(xa[i].z, ma[j].z, accM[i][j]);
                accM[i][j] = fmaf(xa[i].w, ma[j].w, accM[i][j]);
                accR[i][j] = fmaf(xa[i].x, ra[j].x, accR[i][j]);
                accR[i][j] = fmaf(xa[i].y, ra[j].y, accR[i][j]);
                accR[i][j] = fmaf(xa[i].z, ra[j].z, accR[i][j]);
                accR[i][j] = fmaf(xa[i].w, ra[j].w, accR[i][j]);
                accM[i][j] = fmaf(xb[i].x, mb[j].x, accM[i][j]);
                accM[i][j] = fmaf(xb[i].y, mb[j].y, accM[i][j]);
                accM[i][j] = fmaf(xb[i].z, mb[j].z, accM[i][j]);
                accM[i][j] = fmaf(xb[i].w, mb[j].w, accM[i][j]);
                accR[i][j] = fmaf(xb[i].x, rb[j].x, accR[i][j]);
                accR[i][j] = fmaf(xb[i].y, rb[j].y, accR[i][j]);
                accR[i][j] = fmaf(xb[i].z, rb[j].z, accR[i][j]);
                accR[i][j] = fmaf(xb[i].w, rb[j].w, accR[i][j]);
            }
    }
    __syncthreads();   // B2: GEMM1 reads of s0 done

    // write M^T[c][r] into s0
#pragma unroll
    for (int j = 0; j < 3; j++)
#pragma unroll
        for (int i = 0; i < 3; i++)
            s0[(c0 + j) * STRD + (r0 + i)] = accM[i][j];
    __syncthreads();   // B3: M visible

    // ---- GEMM2 (pipelined): h = bias + R + A@M ----
    float h[3][3];
#pragma unroll
    for (int j = 0; j < 3; j++) {
        float bj = (c0 + j < NG) ? bias[c0 + j] : 0.f;
#pragma unroll
        for (int i = 0; i < 3; i++) h[i][j] = accR[i][j] + bj;
    }
    {
        const float* pA = sA + r0 * STRD;
        const float* pM = s0 + c0 * STRD;
        float4 aa[3], sa[3], ab[3], sb[3];
#pragma unroll
        for (int i = 0; i < 3; i++) {
            aa[i] = *(const float4*)(pA + i * STRD);
            sa[i] = *(const float4*)(pM + i * STRD);
        }
#pragma unroll 2
        for (int k = 0; k < 88; k += 8) {
#pragma unroll
            for (int i = 0; i < 3; i++) {
                ab[i] = *(const float4*)(pA + i * STRD + k + 4);
                sb[i] = *(const float4*)(pM + i * STRD + k + 4);
            }
#pragma unroll
            for (int i = 0; i < 3; i++)
#pragma unroll
                for (int j = 0; j < 3; j++) {
                    h[i][j] = fmaf(aa[i].x, sa[j].x, h[i][j]);
                    h[i][j] = fmaf(aa[i].y, sa[j].y, h[i][j]);
                    h[i][j] = fmaf(aa[i].z, sa[j].z, h[i][j]);
                    h[i][j] = fmaf(aa[i].w, sa[j].w, h[i][j]);
                }
#pragma unroll
            for (int i = 0; i < 3; i++) {
                aa[i] = *(const float4*)(pA + i * STRD + k + 8);
                sa[i] = *(const float4*)(pM + i * STRD + k + 8);
            }
#pragma unroll
            for (int i = 0; i < 3; i++)
#pragma unroll
                for (int j = 0; j < 3; j++) {
                    h[i][j] = fmaf(ab[i].x, sb[j].x, h[i][j]);
                    h[i][j] = fmaf(ab[i].y, sb[j].y, h[i][j]);
                    h[i][j] = fmaf(ab[i].z, sb[j].z, h[i][j]);
                    h[i][j] = fmaf(ab[i].w, sb[j].w, h[i][j]);
                }
        }
#pragma unroll
        for (int i = 0; i < 3; i++) {
            ab[i] = *(const float4*)(pA + i * STRD + 92);
            sb[i] = *(const float4*)(pM + i * STRD + 92);
        }
#pragma unroll
        for (int i = 0; i < 3; i++)
#pragma unroll
            for (int j = 0; j < 3; j++) {
                h[i][j] = fmaf(aa[i].x, sa[j].x, h[i][j]);
                h[i][j] = fmaf(aa[i].y, sa[j].y, h[i][j]);
                h[i][j] = fmaf(aa[i].z, sa[j].z, h[i][j]);
                h[i][j] = fmaf(aa[i].w, sa[j].w, h[i][j]);
                h[i][j] = fmaf(ab[i].x, sb[j].x, h[i][j]);
                h[i][j] = fmaf(ab[i].y, sb[j].y, h[i][j]);
                h[i][j] = fmaf(ab[i].z, sb[j].z, h[i][j]);
                h[i][j] = fmaf(ab[i].w, sb[j].w, h[i][j]);
            }
    }

    // ---- relu + global store + BN partial stats ----
    float cs[3] = {0.f,0.f,0.f}, cq[3] = {0.f,0.f,0.f};
#pragma unroll
    for (int i = 0; i < 3; i++) {
        int r = r0 + i;
        if (r < NG) {
#pragma unroll
            for (int j = 0; j < 3; j++) {
                int c = c0 + j;
                if (c < NG) {
                    float v = fmaxf(h[i][j], 0.f);
                    hout[(size_t)(g * NG + r) * NG + c] = v;
                    cs[j] += v; cq[j] += v * v;
                }
            }
        }
    }
    // reduce over the wave's 8 row-groups (lane bits 3..5)
#pragma unroll
    for (int m = 8; m < 64; m <<= 1) {
#pragma unroll
        for (int j = 0; j < 3; j++) {
            cs[j] += __shfl_xor(cs[j], m);
            cq[j] += __shfl_xor(cq[j], m);
        }
    }
    if (lr == 0) {
#pragma unroll
        for (int j = 0; j < 3; j++) {
            int c = c0 + j;
            if (c < NG) { atomicAdd(&sSum[c], cs[j]); atomicAdd(&sSq[c], cq[j]); }
        }
    }
    __syncthreads();
    // per-block partials (plain stores -> no global zero-init needed)
    if (tid < 96) psOut[g * 192 + tid] = sSum[tid];
    else if (tid < 192) psOut[g * 192 + tid] = sSq[tid - 96];

    // ---- folded classifier prep (layer 1 only) ----
    if (do_prep) {
        if (wave < 4) {
            int row = g + 256 * wave;
            if (row < 900) {
                const float* rw = linW + (size_t)row * 1801;
                float acc = 0.f;
                for (int c2 = lane; c2 < 1801; c2 += 64) acc += rw[c2] * clsW[c2];
                for (int off = 32; off; off >>= 1) acc += __shfl_down(acc, off);
                if (lane == 0) vlin[row] = acc;
            }
        } else if (g == 0 && wave == 4) {
            float acc = 0.f;
            for (int c2 = lane; c2 < 1801; c2 += 64) acc += linb[c2] * clsW[c2];
            for (int off = 32; off; off >>= 1) acc += __shfl_down(acc, off);
            if (lane == 0) scal[0] = acc + clsb[0];
        } else if (g == 0 && wave == 5) {
            float acc = 0.f;
            for (int c2 = lane; c2 < NG; c2 += 64) acc += poolp[c2] * poolp[c2];
            for (int off = 32; off; off >>= 1) acc += __shfl_down(acc, off);
            if (lane == 0) scal[1] = rsqrtf(acc);
        }
    }
}

// ---------------- pooling + classifier ----------------
__global__ __launch_bounds__(256)
void final_kernel(const float* __restrict__ h2, const float* __restrict__ psIn,
                  const float* __restrict__ poolp,
                  const float* __restrict__ vlin, const float* __restrict__ scal,
                  float* __restrict__ out)
{
    __shared__ float sXN[NG * 91];
    __shared__ float sMu[96], sRs[96], sP[96], sStat[192];
    __shared__ float sScore[NG];
    __shared__ int   sIdx[KK];
    __shared__ float sVal[KK];
    __shared__ float sRed[4];
    const int g = blockIdx.x, tid = threadIdx.x;

    if (tid < 192) {
        float s = 0.f;
        const float* p = psIn + tid;
#pragma unroll 8
        for (int b = 0; b < NB; b++) s += p[b * 192];
        sStat[tid] = s;
    }
    __syncthreads();
    if (tid < NG) {
        float m = sStat[tid] * (1.f / NTOT);
        float v = sStat[96 + tid] * (1.f / NTOT) - m * m;
        sMu[tid] = m; sRs[tid] = rsqrtf(v + 1e-5f);
        sP[tid] = poolp[tid];
    }
    __syncthreads();

    const float* hg = h2 + (size_t)g * (NG * NG);
    for (int idx = tid; idx < NG * NG; idx += 256) {
        int d = idx / NG, f = idx - (idx / NG) * NG;
        sXN[d * 91 + f] = (hg[idx] - sMu[f]) * sRs[f];
    }
    __syncthreads();

    if (tid < NG) {
        float s = 0.f;
        for (int f = 0; f < NG; f++) s += sXN[tid * 91 + f] * sP[f];
        sScore[tid] = 0.7f * tanhf(s * scal[1]);
    }
    __syncthreads();

    // wave-parallel top-10 (ties -> lower index, matching lax.top_k)
    if (tid < 64) {
        float va = sScore[tid];
        float vb = (tid + 64 < NG) ? sScore[tid + 64] : -1e30f;
        int ia = tid, ib = tid + 64;
        for (int k = 0; k < KK; k++) {
            float v; int i;
            if (va >= vb) { v = va; i = ia; } else { v = vb; i = ib; }
            for (int off = 1; off < 64; off <<= 1) {
                float v2 = __shfl_xor(v, off);
                int   i2 = __shfl_xor(i, off);
                if (v2 > v || (v2 == v && i2 < i)) { v = v2; i = i2; }
            }
            if (tid == 0) { sIdx[k] = i; sVal[k] = v; }
            if (i == ia) va = -1e30f;
            if (i == ib) vb = -1e30f;
        }
    }
    __syncthreads();

    if (tid < KK) out[NB + g * KK + tid] = (float)(g * NG + sIdx[tid]);

    float acc = 0.f;
    for (int j = tid; j < KK * NG; j += 256) {
        int k = j / NG, f = j - (j / NG) * NG;
        acc += sXN[sIdx[k] * 91 + f] * sVal[k] * vlin[j];
    }
    for (int off = 32; off; off >>= 1) acc += __shfl_down(acc, off);
    if ((tid & 63) == 0) sRed[tid >> 6] = acc;
    __syncthreads();
    if (tid == 0) {
        float tot = sRed[0] + sRed[1] + sRed[2] + sRed[3] + scal[0];
        out[g] = 1.f / (1.f + expf(-tot));
    }
}

// ---------------- host launch ----------------
extern "C" void kernel_launch(void* const* d_in, const int* in_sizes, int n_in,
                              void* d_out, int out_size, void* d_ws, size_t ws_size,
                              hipStream_t stream) {
    const float* x    = (const float*)d_in[0];
    const float* attr = (const float*)d_in[2];
    const float* W1r  = (const float*)d_in[4];
    const float* W1m  = (const float*)d_in[5];
    const float* b1   = (const float*)d_in[6];
    const float* W2r  = (const float*)d_in[7];
    const float* W2m  = (const float*)d_in[8];
    const float* b2   = (const float*)d_in[9];
    const float* poolp= (const float*)d_in[10];
    const float* linW = (const float*)d_in[11];
    const float* linb = (const float*)d_in[12];
    const float* clsW = (const float*)d_in[13];
    const float* clsb = (const float*)d_in[14];

    float* ws   = (float*)d_ws;
    float* ps1  = ws;                         // 256*192 per-block stats, layer1
    float* ps2  = ps1 + NB * 192;             // 256*192, layer2
    float* vlin = ps2 + NB * 192;             // 900
    float* scal = vlin + 900;                 // 2
    float* h1   = scal + 62;                  // align; 23040*90
    float* h2   = h1 + (size_t)NTOT * NG;

    const size_t smem = SM_FLOATS * sizeof(float);   // 153,600 B
    hipFuncSetAttribute((const void*)layer_kernel, hipFuncAttributeMaxDynamicSharedMemorySize, (int)smem);

    layer_kernel<<<NB, 1024, smem, stream>>>(x,  nullptr, 0, attr, W1m, W1r, b1, h1, ps1,
                                             1, linW, linb, clsW, clsb, poolp, vlin, scal);
    layer_kernel<<<NB, 1024, smem, stream>>>(h1, ps1, 1, attr, W2m, W2r, b2, h2, ps2,
                                             0, linW, linb, clsW, clsb, poolp, vlin, scal);
    final_kernel<<<NB, 256, 0, stream>>>(h2, ps2, poolp, vlin, scal, (float*)d_out);
}